// Round 19
// baseline (104.054 us; speedup 1.0000x reference)
//
#include <hip/hip_runtime.h>
#include <hip/hip_bf16.h>

#define NEG_SLOPE 0.01f
#define NPB 512          // nodes per coarse bucket (dst >> 9)
#define QN  128          // nodes per merged block (quarter bucket)
#define QCAP 2600        // per-quarter edge capacity (mean 2048 + 12 sigma)
#define CHUNK 4096       // edges per block in partition pass

typedef __attribute__((ext_vector_type(8))) short short8;
typedef __attribute__((ext_vector_type(4))) float f32x4;

__device__ __forceinline__ unsigned short f2bf_rne(float f) {
    __hip_bfloat16 b = __float2bfloat16(f);       // HW v_cvt, RNE
    return __builtin_bit_cast(unsigned short, b);
}

__device__ __forceinline__ short8 cvt2(float4 v0, float4 v1) {
    short8 o;
    o[0]=(short)f2bf_rne(v0.x); o[1]=(short)f2bf_rne(v0.y);
    o[2]=(short)f2bf_rne(v0.z); o[3]=(short)f2bf_rne(v0.w);
    o[4]=(short)f2bf_rne(v1.x); o[5]=(short)f2bf_rne(v1.y);
    o[6]=(short)f2bf_rne(v1.z); o[7]=(short)f2bf_rne(v1.w);
    return o;
}

// 64-wide inclusive wave scan (no barriers).
__device__ __forceinline__ unsigned wscan_incl(unsigned v) {
    const int ln = threadIdx.x & 63;
#pragma unroll
    for (int off = 1; off < 64; off <<= 1) {
        unsigned x = __shfl_up(v, off);
        if (ln >= off) v += x;
    }
    return v;
}

// Fused K1 (r16-proven): blocks [0, G1) = MFMA GEMM (z bf16 + s,t);
// blocks [G1, G1+G2) = edge partition pass.
__global__ __launch_bounds__(256, 4) void k_gp(
    const float* __restrict__ h, const float* __restrict__ W1,
    const float* __restrict__ Wa, unsigned short* __restrict__ zb,
    float* __restrict__ s, float* __restrict__ t, int N, int G1,
    const int* __restrict__ src, const int* __restrict__ dst,
    unsigned* __restrict__ gcur, unsigned* __restrict__ table,
    int E, int NBKT, int BCAP)
{
    __shared__ __align__(16) union SM {
        struct { short wsb[64 * 128]; short tbuf[4][16 * 64]; } g;       // 24 KB
        struct {
            unsigned cnt[256]; unsigned exc[256]; unsigned sbuf[256];
            unsigned gbaseb[256]; unsigned stage[CHUNK];
            unsigned short bkt[CHUNK];
        } p;                                                             // 28 KB
    } sm;
    const int tid = threadIdx.x;

    if (blockIdx.x < (unsigned)G1) {
        // ---------------- GEMM path ----------------
        const int nb = blockIdx.x * 256;
        const int w  = tid >> 6;
        const int l  = tid & 63;
        const int lr = l & 15;
        const int lc = l >> 4;
        const int rowbase = nb + w * 64;
        const float4* __restrict__ h4 = (const float4*)h;
        const float4* __restrict__ W14 = (const float4*)W1;

        float asrc[4], adst[4];
#pragma unroll
        for (int ni = 0; ni < 4; ++ni) {
            asrc[ni] = Wa[ni * 16 + lr];
            adst[ni] = Wa[64 + ni * 16 + lr];
        }

        float4 av[8];
        {
            const int myn = rowbase + lr;
#pragma unroll
            for (int ks = 0; ks < 4; ++ks) {
                const int kcb = ks * 4 + lc;
                if (myn < N) {
                    av[2 * ks]     = h4[(size_t)myn * 32 + kcb * 2];
                    av[2 * ks + 1] = h4[(size_t)myn * 32 + kcb * 2 + 1];
                } else {
                    av[2 * ks]     = make_float4(0.f, 0.f, 0.f, 0.f);
                    av[2 * ks + 1] = make_float4(0.f, 0.f, 0.f, 0.f);
                }
            }
        }

#pragma unroll
        for (int it = 0; it < 4; ++it) {
            const int q = tid + it * 256;
            const int r = q >> 4, cb = q & 15;
            float4 v0 = W14[(size_t)r * 32 + cb * 2];
            float4 v1 = W14[(size_t)r * 32 + cb * 2 + 1];
            *(short8*)&sm.g.wsb[r * 128 + ((cb * 8) ^ ((r & 7) << 3))] = cvt2(v0, v1);
        }
        __syncthreads();

        short* __restrict__ tb = sm.g.tbuf[w];      // per-wave, no barriers

#pragma unroll
        for (int rg = 0; rg < 4; ++rg) {
            short8 afr[4];
#pragma unroll
            for (int ks = 0; ks < 4; ++ks) afr[ks] = cvt2(av[2 * ks], av[2 * ks + 1]);
            if (rg < 3) {
                const int myn = rowbase + (rg + 1) * 16 + lr;
#pragma unroll
                for (int ks = 0; ks < 4; ++ks) {
                    const int kcb = ks * 4 + lc;
                    if (myn < N) {
                        av[2 * ks]     = h4[(size_t)myn * 32 + kcb * 2];
                        av[2 * ks + 1] = h4[(size_t)myn * 32 + kcb * 2 + 1];
                    } else {
                        av[2 * ks]     = make_float4(0.f, 0.f, 0.f, 0.f);
                        av[2 * ks + 1] = make_float4(0.f, 0.f, 0.f, 0.f);
                    }
                }
            }

            f32x4 acc[4];
#pragma unroll
            for (int ni = 0; ni < 4; ++ni) acc[ni] = (f32x4){0.f, 0.f, 0.f, 0.f};
#pragma unroll
            for (int ks = 0; ks < 4; ++ks) {
                const int kcb = ks * 4 + lc;
#pragma unroll
                for (int ni = 0; ni < 4; ++ni) {
                    const int wr = ni * 16 + lr;
                    const short8 bf = *(const short8*)&sm.g.wsb[wr * 128 + ((kcb * 8) ^ ((wr & 7) << 3))];
                    acc[ni] = __builtin_amdgcn_mfma_f32_16x16x32_bf16(afr[ks], bf, acc[ni], 0, 0, 0);
                }
            }

            // s,t epilogue (f32 acc). C/D: col = lr, row = lc*4 + r.
#pragma unroll
            for (int r = 0; r < 4; ++r) {
                float ps = 0.f, pt = 0.f;
#pragma unroll
                for (int ni = 0; ni < 4; ++ni) {
                    ps = fmaf(acc[ni][r], asrc[ni], ps);
                    pt = fmaf(acc[ni][r], adst[ni], pt);
                }
#pragma unroll
                for (int m = 1; m < 16; m <<= 1) {
                    ps += __shfl_xor(ps, m);
                    pt += __shfl_xor(pt, m);
                }
                const int node = rowbase + rg * 16 + lc * 4 + r;
                if (lr == 0 && node < N) { s[node] = ps; t[node] = pt; }
            }

            // z transpose via per-wave LDS -> coalesced 16B stores.
#pragma unroll
            for (int ni = 0; ni < 4; ++ni) {
                const int col = ni * 16 + lr;
#pragma unroll
                for (int r = 0; r < 4; ++r) {
                    const int ro = lc * 4 + r;
                    tb[ro * 64 + (((col >> 3) ^ (ro & 7)) << 3) + (col & 7)]
                        = (short)f2bf_rne(acc[ni][r]);
                }
            }
            {
                const int ro = l >> 2;
                const int n = rowbase + rg * 16 + ro;
                if (n < N) {
#pragma unroll
                    for (int j = 0; j < 2; ++j) {
                        const int c = (l & 3) * 2 + j;
                        const short8 v = *(const short8*)&tb[ro * 64 + ((c ^ (ro & 7)) << 3)];
                        *(short8*)&zb[(size_t)n * 64 + c * 8] = v;
                    }
                }
            }
        }
    } else {
        // ---------------- Partition path ----------------
        const int e0 = (blockIdx.x - G1) * CHUNK;
        const int nE = min(CHUNK, E - e0);

        sm.p.cnt[tid] = 0u;
        __syncthreads();
        for (int i = tid; i < nE; i += 256)
            atomicAdd(&sm.p.cnt[(unsigned)dst[e0 + i] >> 9], 1u);
        __syncthreads();

        const unsigned myc = sm.p.cnt[tid];
        if (tid < NBKT && myc > 0u) sm.p.gbaseb[tid] = atomicAdd(&gcur[tid], myc);

        sm.p.sbuf[tid] = myc;
        __syncthreads();
        for (int off = 1; off < 256; off <<= 1) {
            unsigned x = (tid >= off) ? sm.p.sbuf[tid - off] : 0u;
            __syncthreads();
            sm.p.sbuf[tid] += x;
            __syncthreads();
        }
        sm.p.exc[tid] = sm.p.sbuf[tid] - myc;
        __syncthreads();
        sm.p.cnt[tid] = 0u;
        __syncthreads();

        for (int i = tid; i < nE; i += 256) {
            const unsigned d = (unsigned)dst[e0 + i];
            const unsigned b = d >> 9;
            const unsigned pos = sm.p.exc[b] + atomicAdd(&sm.p.cnt[b], 1u);
            sm.p.stage[pos] = ((unsigned)src[e0 + i] << 9) | (d & 511u);
            sm.p.bkt[pos] = (unsigned short)b;
        }
        __syncthreads();

        for (int i = tid; i < nE; i += 256) {
            const unsigned b = sm.p.bkt[i];
            const unsigned off = sm.p.gbaseb[b] + ((unsigned)i - sm.p.exc[b]);
            if (off < (unsigned)BCAP)
                table[(size_t)b * BCAP + off] = sm.p.stage[i];
        }
    }
}

// Merged softmax + aggregate. One block per QUARTER bucket (128 nodes).
// Pass 1: count my quarter's edges per node. Scan. Pass 2: place (p, src)
// sorted INTO LDS + LDS-atomic denominator (direct shared-array expression —
// no derived pointers). Phase B: k_node's 16-lane/node register gather-
// accumulate, edge list read from LDS. No edge_ps/offsets/invden globals.
__global__ __launch_bounds__(256) void k_sn(
    const unsigned* __restrict__ table, const unsigned* __restrict__ gcur,
    const float* __restrict__ s, const float* __restrict__ t,
    const unsigned short* __restrict__ zb, float* __restrict__ out,
    int N, int BCAP)
{
    __shared__ unsigned ncnt[QN], nexc[QN], scur[QN];
    __shared__ float tl[QN], den[QN], invd[QN];
    __shared__ unsigned wtot[2];
    __shared__ __align__(8) uint2 elist[QCAP];   // 20.8 KB

    const int tid = threadIdx.x;
    const int b  = blockIdx.x >> 2;
    const int qr = blockIdx.x & 3;
    const int node0 = b * NPB + qr * QN;
    const int bc = min((int)gcur[b], BCAP);
    const size_t tbo = (size_t)b * BCAP;

    if (tid < QN) {
        ncnt[tid] = 0u; scur[tid] = 0u; den[tid] = 0.f;
        const int n = node0 + tid;
        tl[tid] = (n < N) ? t[n] : 0.f;
    }
    __syncthreads();

    // Pass 1: count.
    for (int i = tid; i < bc; i += 256) {
        const unsigned v = table[tbo + i];
        if (((v >> 7) & 3u) == (unsigned)qr)
            atomicAdd(&ncnt[v & 127u], 1u);
    }
    __syncthreads();

    // Exclusive scan of ncnt[128]: 2 wave-scans + cross-wave fix.
    if (tid < QN) {
        const unsigned c = ncnt[tid];
        const unsigned inc = wscan_incl(c);
        if ((tid & 63) == 63) wtot[tid >> 6] = inc;
        nexc[tid] = inc - c;
    }
    __syncthreads();
    if (tid >= 64 && tid < QN) nexc[tid] += wtot[0];
    __syncthreads();

    // Pass 2: compute p, place sorted into LDS, accumulate den.
    for (int i = tid; i < bc; i += 256) {
        const unsigned v = table[tbo + i];
        if (((v >> 7) & 3u) != (unsigned)qr) continue;
        const unsigned l = v & 127u;
        const unsigned sj = v >> 9;
        float e = s[sj] + tl[l];
        e = (e >= 0.f) ? e : NEG_SLOPE * e;
        const float p = __expf(e);
        const unsigned pos = nexc[l] + atomicAdd(&scur[l], 1u);
        if (pos < (unsigned)QCAP) {
            elist[pos] = make_uint2(__float_as_uint(p), sj);
            atomicAdd(&den[l], p);
        }
    }
    __syncthreads();
    if (tid < QN) invd[tid] = 1.f / fmaxf(den[tid], 1e-16f);
    __syncthreads();

    // Phase B: 16 lanes/node, 4 nodes/wave, 8 node-groups.
    const int wl    = tid & 63;
    const int w     = tid >> 6;
    const int gbase = wl & ~15;
    const int sub   = wl & 15;
    const int g2    = sub >> 3;
    const int l8    = sub & 7;
    const unsigned short* __restrict__ zrow = zb + l8 * 8;

    for (int grp = 0; grp < 8; ++grp) {
        const int l  = grp * 16 + w * 4 + (wl >> 4);   // local node 0..127
        const int gn = node0 + l;
        const unsigned beg = nexc[l];
        const int cnt = (int)ncnt[l];

        float acc[8] = {0.f, 0.f, 0.f, 0.f, 0.f, 0.f, 0.f, 0.f};
        for (int base = 0; base < cnt; base += 16) {
            const int rem = cnt - base;
            uint2 ep = make_uint2(0u, 0u);              // p=0, sj=0 inactive
            if (sub < rem) ep = elist[beg + base + sub];
            const float p = __uint_as_float(ep.x);
            const int  sj = (int)ep.y;

            uint4 vv[8];
#pragma unroll
            for (int k = 0; k < 8; ++k) {
                const int sjj = __shfl(sj, gbase + g2 * 8 + k);
                vv[k] = *(const uint4*)&zrow[(size_t)sjj * 64];
            }
#pragma unroll
            for (int k = 0; k < 8; ++k) {
                const float pj = __shfl(p, gbase + g2 * 8 + k);
                const uint4 v = vv[k];
#define UNPK(u, d0) \
                acc[d0]     = fmaf(pj, __uint_as_float((u) << 16),          acc[d0]); \
                acc[d0 + 1] = fmaf(pj, __uint_as_float((u) & 0xFFFF0000u), acc[d0 + 1]);
                UNPK(v.x, 0) UNPK(v.y, 2) UNPK(v.z, 4) UNPK(v.w, 6)
#undef UNPK
            }
        }

#pragma unroll
        for (int c = 0; c < 8; ++c)
            acc[c] += __shfl_xor(acc[c], 8);

        if (sub < 8 && gn < N) {
            const float iv = invd[l];
            float4 o0 = make_float4(acc[0] * iv, acc[1] * iv, acc[2] * iv, acc[3] * iv);
            float4 o1 = make_float4(acc[4] * iv, acc[5] * iv, acc[6] * iv, acc[7] * iv);
            *(float4*)&out[(size_t)gn * 64 + sub * 8]     = o0;
            *(float4*)&out[(size_t)gn * 64 + sub * 8 + 4] = o1;
        }
    }
}

extern "C" void kernel_launch(void* const* d_in, const int* in_sizes, int n_in,
                              void* d_out, int out_size, void* d_ws, size_t ws_size,
                              hipStream_t stream) {
    const float* h   = (const float*)d_in[0];
    const int*   src = (const int*)d_in[1];
    const int*   dst = (const int*)d_in[2];
    const float* W1  = (const float*)d_in[3];
    const float* Wa  = (const float*)d_in[4];
    float* out = (float*)d_out;

    const int N = in_sizes[0] / 128;
    const int E = in_sizes[1];
    const int NBKT = (N + NPB - 1) / NPB;            // <=256
    const int meanb = (E + NBKT - 1) / NBKT;
    int slack = 24 * (int)sqrtf((float)meanb) + 64;  // mean + 24 sigma
    const int BCAP = meanb + slack;

    const int G1 = (N + 255) / 256;                  // gemm blocks
    const int G2 = (E + CHUNK - 1) / CHUNK;          // partition blocks

    // ws: zb(N*64 bf16) | s(N) | t(N) | gcur(NBKT) | table(NBKT*BCAP)
    unsigned short* zb = (unsigned short*)d_ws;
    float*    s        = (float*)(zb + (size_t)N * 64);
    float*    t        = s + N;
    unsigned* gcur     = (unsigned*)(t + N);
    unsigned* table    = gcur + NBKT;

    hipMemsetAsync(gcur, 0, (size_t)NBKT * sizeof(unsigned), stream);

    k_gp<<<G1 + G2, 256, 0, stream>>>(h, W1, Wa, zb, s, t, N, G1,
                                      src, dst, gcur, table, E, NBKT, BCAP);
    k_sn<<<NBKT * 4, 256, 0, stream>>>(table, gcur, s, t, zb, out, N, BCAP);
}

// Round 20
// 99.599 us; speedup vs baseline: 1.0447x; 1.0447x over previous
//
#include <hip/hip_runtime.h>
#include <hip/hip_bf16.h>

#define NEG_SLOPE 0.01f
#define NPB 256          // nodes per coarse bucket (dst >> 8)
#define CHUNK 4096       // edges per block in partition pass

typedef __attribute__((ext_vector_type(8))) short short8;
typedef __attribute__((ext_vector_type(4))) float f32x4;

__device__ __forceinline__ unsigned short f2bf_rne(float f) {
    __hip_bfloat16 b = __float2bfloat16(f);       // HW v_cvt, RNE
    return __builtin_bit_cast(unsigned short, b);
}

__device__ __forceinline__ short8 cvt2(float4 v0, float4 v1) {
    short8 o;
    o[0]=(short)f2bf_rne(v0.x); o[1]=(short)f2bf_rne(v0.y);
    o[2]=(short)f2bf_rne(v0.z); o[3]=(short)f2bf_rne(v0.w);
    o[4]=(short)f2bf_rne(v1.x); o[5]=(short)f2bf_rne(v1.y);
    o[6]=(short)f2bf_rne(v1.z); o[7]=(short)f2bf_rne(v1.w);
    return o;
}

// Fused K1: blocks [0, G1) = MFMA GEMM (z bf16 + s,t); blocks [G1, G1+G2) =
// edge partition into 256-node buckets (dst>>8), pack src<<8 | dst&255.
__global__ __launch_bounds__(256, 4) void k_gp(
    const float* __restrict__ h, const float* __restrict__ W1,
    const float* __restrict__ Wa, unsigned short* __restrict__ zb,
    float* __restrict__ s, float* __restrict__ t, int N, int G1,
    const int* __restrict__ src, const int* __restrict__ dst,
    unsigned* __restrict__ gcur, unsigned* __restrict__ table,
    int E, int NBKT, int BCAP)
{
    __shared__ __align__(16) union SM {
        struct { short wsb[64 * 128]; short tbuf[4][16 * 64]; } g;       // 24 KB
        struct {
            unsigned cnt[512]; unsigned exc[512]; unsigned sbuf[512];
            unsigned gbaseb[512];
            unsigned stage[CHUNK]; unsigned short bkt[CHUNK];
        } p;                                                             // 32 KB
    } sm;
    const int tid = threadIdx.x;

    if (blockIdx.x < (unsigned)G1) {
        // ---------------- GEMM path (r16-proven) ----------------
        const int nb = blockIdx.x * 256;
        const int w  = tid >> 6;
        const int l  = tid & 63;
        const int lr = l & 15;
        const int lc = l >> 4;
        const int rowbase = nb + w * 64;
        const float4* __restrict__ h4 = (const float4*)h;
        const float4* __restrict__ W14 = (const float4*)W1;

        float asrc[4], adst[4];
#pragma unroll
        for (int ni = 0; ni < 4; ++ni) {
            asrc[ni] = Wa[ni * 16 + lr];
            adst[ni] = Wa[64 + ni * 16 + lr];
        }

        float4 av[8];
        {
            const int myn = rowbase + lr;
#pragma unroll
            for (int ks = 0; ks < 4; ++ks) {
                const int kcb = ks * 4 + lc;
                if (myn < N) {
                    av[2 * ks]     = h4[(size_t)myn * 32 + kcb * 2];
                    av[2 * ks + 1] = h4[(size_t)myn * 32 + kcb * 2 + 1];
                } else {
                    av[2 * ks]     = make_float4(0.f, 0.f, 0.f, 0.f);
                    av[2 * ks + 1] = make_float4(0.f, 0.f, 0.f, 0.f);
                }
            }
        }

#pragma unroll
        for (int it = 0; it < 4; ++it) {
            const int q = tid + it * 256;
            const int r = q >> 4, cb = q & 15;
            float4 v0 = W14[(size_t)r * 32 + cb * 2];
            float4 v1 = W14[(size_t)r * 32 + cb * 2 + 1];
            *(short8*)&sm.g.wsb[r * 128 + ((cb * 8) ^ ((r & 7) << 3))] = cvt2(v0, v1);
        }
        __syncthreads();

        short* __restrict__ tb = sm.g.tbuf[w];      // per-wave, no barriers

#pragma unroll
        for (int rg = 0; rg < 4; ++rg) {
            short8 afr[4];
#pragma unroll
            for (int ks = 0; ks < 4; ++ks) afr[ks] = cvt2(av[2 * ks], av[2 * ks + 1]);
            if (rg < 3) {
                const int myn = rowbase + (rg + 1) * 16 + lr;
#pragma unroll
                for (int ks = 0; ks < 4; ++ks) {
                    const int kcb = ks * 4 + lc;
                    if (myn < N) {
                        av[2 * ks]     = h4[(size_t)myn * 32 + kcb * 2];
                        av[2 * ks + 1] = h4[(size_t)myn * 32 + kcb * 2 + 1];
                    } else {
                        av[2 * ks]     = make_float4(0.f, 0.f, 0.f, 0.f);
                        av[2 * ks + 1] = make_float4(0.f, 0.f, 0.f, 0.f);
                    }
                }
            }

            f32x4 acc[4];
#pragma unroll
            for (int ni = 0; ni < 4; ++ni) acc[ni] = (f32x4){0.f, 0.f, 0.f, 0.f};
#pragma unroll
            for (int ks = 0; ks < 4; ++ks) {
                const int kcb = ks * 4 + lc;
#pragma unroll
                for (int ni = 0; ni < 4; ++ni) {
                    const int wr = ni * 16 + lr;
                    const short8 bf = *(const short8*)&sm.g.wsb[wr * 128 + ((kcb * 8) ^ ((wr & 7) << 3))];
                    acc[ni] = __builtin_amdgcn_mfma_f32_16x16x32_bf16(afr[ks], bf, acc[ni], 0, 0, 0);
                }
            }

            // s,t epilogue (f32 acc). C/D: col = lr, row = lc*4 + r.
#pragma unroll
            for (int r = 0; r < 4; ++r) {
                float ps = 0.f, pt = 0.f;
#pragma unroll
                for (int ni = 0; ni < 4; ++ni) {
                    ps = fmaf(acc[ni][r], asrc[ni], ps);
                    pt = fmaf(acc[ni][r], adst[ni], pt);
                }
#pragma unroll
                for (int m = 1; m < 16; m <<= 1) {
                    ps += __shfl_xor(ps, m);
                    pt += __shfl_xor(pt, m);
                }
                const int node = rowbase + rg * 16 + lc * 4 + r;
                if (lr == 0 && node < N) { s[node] = ps; t[node] = pt; }
            }

            // z transpose via per-wave LDS -> coalesced 16B stores.
#pragma unroll
            for (int ni = 0; ni < 4; ++ni) {
                const int col = ni * 16 + lr;
#pragma unroll
                for (int r = 0; r < 4; ++r) {
                    const int ro = lc * 4 + r;
                    tb[ro * 64 + (((col >> 3) ^ (ro & 7)) << 3) + (col & 7)]
                        = (short)f2bf_rne(acc[ni][r]);
                }
            }
            {
                const int ro = l >> 2;
                const int n = rowbase + rg * 16 + ro;
                if (n < N) {
#pragma unroll
                    for (int j = 0; j < 2; ++j) {
                        const int c = (l & 3) * 2 + j;
                        const short8 v = *(const short8*)&tb[ro * 64 + ((c ^ (ro & 7)) << 3)];
                        *(short8*)&zb[(size_t)n * 64 + c * 8] = v;
                    }
                }
            }
        }
    } else {
        // ---------------- Partition path (512-bucket arrays, 2/thread) ----
        const int e0 = (blockIdx.x - G1) * CHUNK;
        const int nE = min(CHUNK, E - e0);

        sm.p.cnt[tid] = 0u; sm.p.cnt[tid + 256] = 0u;
        __syncthreads();
        for (int i = tid; i < nE; i += 256)
            atomicAdd(&sm.p.cnt[(unsigned)dst[e0 + i] >> 8], 1u);
        __syncthreads();

        // reserve global space: one atomic per non-empty bucket
        for (int j = tid; j < NBKT; j += 256) {
            const unsigned myc = sm.p.cnt[j];
            if (myc > 0u) sm.p.gbaseb[j] = atomicAdd(&gcur[j], myc);
        }

        // exclusive scan of 512 entries with 256 threads (2 elems/thread)
        const unsigned c0 = sm.p.cnt[tid], c1 = sm.p.cnt[tid + 256];
        sm.p.sbuf[tid] = c0; sm.p.sbuf[tid + 256] = c1;
        __syncthreads();
        for (int off = 1; off < 512; off <<= 1) {
            unsigned x0 = (tid >= off) ? sm.p.sbuf[tid - off] : 0u;
            unsigned x1 = (tid + 256 >= off) ? sm.p.sbuf[tid + 256 - off] : 0u;
            __syncthreads();
            sm.p.sbuf[tid] += x0; sm.p.sbuf[tid + 256] += x1;
            __syncthreads();
        }
        sm.p.exc[tid] = sm.p.sbuf[tid] - c0;
        sm.p.exc[tid + 256] = sm.p.sbuf[tid + 256] - c1;
        __syncthreads();
        sm.p.cnt[tid] = 0u; sm.p.cnt[tid + 256] = 0u;   // reuse as cursors
        __syncthreads();

        for (int i = tid; i < nE; i += 256) {
            const unsigned d = (unsigned)dst[e0 + i];
            const unsigned b = d >> 8;
            const unsigned pos = sm.p.exc[b] + atomicAdd(&sm.p.cnt[b], 1u);
            sm.p.stage[pos] = ((unsigned)src[e0 + i] << 8) | (d & 255u);
            sm.p.bkt[pos] = (unsigned short)b;
        }
        __syncthreads();

        for (int i = tid; i < nE; i += 256) {
            const unsigned b = sm.p.bkt[i];
            const unsigned off = sm.p.gbaseb[b] + ((unsigned)i - sm.p.exc[b]);
            if (off < (unsigned)BCAP)
                table[(size_t)b * BCAP + off] = sm.p.stage[i];
        }
    }
}

// Pass B (one block of 512 per 256-node bucket): recompute global prefix,
// LDS histogram+scan over 256 nodes, scatter WITH softmax numerator
// p = exp(leaky(s[src]+t[dst])) and LDS-atomic denominator.
__global__ __launch_bounds__(512) void k_sp(
    const unsigned* __restrict__ table, const unsigned* __restrict__ gcur,
    const float* __restrict__ s, const float* __restrict__ t,
    uint2* __restrict__ edge_ps, unsigned* __restrict__ offsets,
    unsigned* __restrict__ counts, float* __restrict__ invden,
    int N, int NBKT, int BCAP)
{
    __shared__ unsigned ncnt[NPB], nexc[NPB], scur[NPB], sbuf[512];
    __shared__ float tlds[NPB], den[NPB];
    __shared__ unsigned basesh;
    const int tid = threadIdx.x;
    const int b = blockIdx.x;
    const int bc = min((int)gcur[b], BCAP);
    const size_t tbo = (size_t)b * BCAP;
    const int node = b * NPB + tid;

    // global base = exclusive prefix of clamped bucket totals at index b
    {
        unsigned c = (tid < NBKT) ? min(gcur[tid], (unsigned)BCAP) : 0u;
        sbuf[tid] = c;
        __syncthreads();
        for (int off = 1; off < 512; off <<= 1) {
            unsigned x = (tid >= off) ? sbuf[tid - off] : 0u;
            __syncthreads();
            sbuf[tid] += x;
            __syncthreads();
        }
        if (tid == 0) basesh = (b == 0) ? 0u : sbuf[b - 1];
    }
    if (tid < NPB) {
        tlds[tid] = (node < N) ? t[node] : 0.f;
        den[tid] = 0.f;
        ncnt[tid] = 0u;
    }
    __syncthreads();
    const unsigned base = basesh;

    for (int i = tid; i < bc; i += 512)
        atomicAdd(&ncnt[table[tbo + i] & 255u], 1u);
    __syncthreads();

    unsigned c0 = 0u;
    if (tid < NPB) { c0 = ncnt[tid]; sbuf[tid] = c0; }
    __syncthreads();
    for (int off = 1; off < NPB; off <<= 1) {
        unsigned x = (tid >= off && tid < NPB) ? sbuf[tid - off] : 0u;
        __syncthreads();
        if (tid < NPB) sbuf[tid] += x;
        __syncthreads();
    }
    if (tid < NPB) {
        nexc[tid] = sbuf[tid] - c0;
        scur[tid] = 0u;
        if (node < N) { offsets[node] = base + nexc[tid]; counts[node] = c0; }
    }
    __syncthreads();

    for (int i = tid; i < bc; i += 512) {
        const unsigned v = table[tbo + i];
        const unsigned l = v & 255u;
        const unsigned sj = v >> 8;
        float e = s[sj] + tlds[l];
        e = (e >= 0.f) ? e : NEG_SLOPE * e;
        const float p = __expf(e);
        const unsigned pos = nexc[l] + atomicAdd(&scur[l], 1u);
        edge_ps[base + pos] = make_uint2(__float_as_uint(p), sj);
        atomicAdd(&den[l], p);
    }
    __syncthreads();
    if (tid < NPB && node < N) invden[node] = 1.f / fmaxf(den[tid], 1e-16f);
}

// Pure gather-accumulate: out[node] = invden * sum p_j * z[src_j].
__global__ __launch_bounds__(256) void k_node(
    const unsigned* __restrict__ offsets, const unsigned* __restrict__ counts,
    const uint2* __restrict__ edge_ps, const float* __restrict__ invden,
    const unsigned short* __restrict__ zb, float* __restrict__ out, int N)
{
    const int tid = threadIdx.x;
    const int node = blockIdx.x * 16 + (tid >> 4);
    if (node >= N) return;
    const int wl    = tid & 63;
    const int gbase = wl & ~15;
    const int sub   = wl & 15;
    const int g2    = sub >> 3;        // edge half (0/1)
    const int l8    = sub & 7;         // dim slice

    const unsigned beg = offsets[node];
    const int cnt = (int)counts[node];
    if (cnt == 0) {
        if (sub < 8) {
            const float4 zz = make_float4(0.f, 0.f, 0.f, 0.f);
            *(float4*)&out[(size_t)node * 64 + sub * 8]     = zz;
            *(float4*)&out[(size_t)node * 64 + sub * 8 + 4] = zz;
        }
        return;
    }

    const float invd = invden[node];
    const unsigned short* __restrict__ zrow = zb + l8 * 8;
    float acc[8] = {0.f, 0.f, 0.f, 0.f, 0.f, 0.f, 0.f, 0.f};

    for (int base = 0; base < cnt; base += 16) {
        const int rem = cnt - base;
        uint2 ep = make_uint2(0u, 0u);          // p=0, sj=0 for inactive slots
        if (sub < rem) ep = edge_ps[beg + base + sub];
        const float p = __uint_as_float(ep.x);
        const int  sj = (int)ep.y;

        uint4 vv[8];
#pragma unroll
        for (int k = 0; k < 8; ++k) {
            const int sjj = __shfl(sj, gbase + g2 * 8 + k);
            vv[k] = *(const uint4*)&zrow[(size_t)sjj * 64];
        }
#pragma unroll
        for (int k = 0; k < 8; ++k) {
            const float pj = __shfl(p, gbase + g2 * 8 + k);
            const uint4 v = vv[k];
#define UNPK(u, d0) \
            acc[d0]     = fmaf(pj, __uint_as_float((u) << 16),          acc[d0]); \
            acc[d0 + 1] = fmaf(pj, __uint_as_float((u) & 0xFFFF0000u), acc[d0 + 1]);
            UNPK(v.x, 0) UNPK(v.y, 2) UNPK(v.z, 4) UNPK(v.w, 6)
#undef UNPK
        }
    }

#pragma unroll
    for (int c = 0; c < 8; ++c)
        acc[c] += __shfl_xor(acc[c], 8);

    if (sub < 8) {
        float4 o0 = make_float4(acc[0] * invd, acc[1] * invd, acc[2] * invd, acc[3] * invd);
        float4 o1 = make_float4(acc[4] * invd, acc[5] * invd, acc[6] * invd, acc[7] * invd);
        *(float4*)&out[(size_t)node * 64 + sub * 8]     = o0;
        *(float4*)&out[(size_t)node * 64 + sub * 8 + 4] = o1;
    }
}

extern "C" void kernel_launch(void* const* d_in, const int* in_sizes, int n_in,
                              void* d_out, int out_size, void* d_ws, size_t ws_size,
                              hipStream_t stream) {
    const float* h   = (const float*)d_in[0];
    const int*   src = (const int*)d_in[1];
    const int*   dst = (const int*)d_in[2];
    const float* W1  = (const float*)d_in[3];
    const float* Wa  = (const float*)d_in[4];
    float* out = (float*)d_out;

    const int N = in_sizes[0] / 128;
    const int E = in_sizes[1];
    const int NBKT = (N + NPB - 1) / NPB;            // <=512
    const int meanb = (E + NBKT - 1) / NBKT;
    int slack = 24 * (int)sqrtf((float)meanb) + 64;  // mean + 24 sigma
    const int BCAP = meanb + slack;

    const int G1 = (N + 255) / 256;                  // gemm blocks (256 rows each)
    const int G2 = (E + CHUNK - 1) / CHUNK;          // partition blocks

    // ws: zb(N*64 bf16) | s(N) | t(N) | gcur(NBKT) | offsets(N) | counts(N) |
    //     invden(N) | edge_ps(E u64) | table(NBKT*BCAP)
    unsigned short* zb = (unsigned short*)d_ws;
    float*    s        = (float*)(zb + (size_t)N * 64);
    float*    t        = s + N;
    unsigned* gcur     = (unsigned*)(t + N);
    unsigned* offsets  = gcur + NBKT;
    unsigned* counts   = offsets + N;
    float*    invden   = (float*)(counts + N);
    uint2*    edge_ps  = (uint2*)(invden + N);
    unsigned* table    = (unsigned*)(edge_ps + E);

    hipMemsetAsync(gcur, 0, (size_t)NBKT * sizeof(unsigned), stream);

    k_gp<<<G1 + G2, 256, 0, stream>>>(h, W1, Wa, zb, s, t, N, G1,
                                      src, dst, gcur, table, E, NBKT, BCAP);
    k_sp<<<NBKT, 512, 0, stream>>>(table, gcur, s, t, edge_ps, offsets, counts,
                                   invden, N, NBKT, BCAP);
    k_node<<<(N + 15) / 16, 256, 0, stream>>>(offsets, counts, edge_ps, invden, zb, out, N);
}

// Round 21
// 95.504 us; speedup vs baseline: 1.0895x; 1.0429x over previous
//
#include <hip/hip_runtime.h>
#include <hip/hip_bf16.h>

#define NEG_SLOPE 0.01f
#define NPB 512          // nodes per coarse bucket (dst >> 9)
#define CHUNK 4096       // edges per block in partition pass

typedef __attribute__((ext_vector_type(8))) short short8;
typedef __attribute__((ext_vector_type(4))) float f32x4;

__device__ __forceinline__ unsigned short f2bf_rne(float f) {
    unsigned u = __float_as_uint(f);
    u += 0x7FFFu + ((u >> 16) & 1u);       // round-to-nearest-even
    return (unsigned short)(u >> 16);
}

// Fused K1: blocks [0, G1) = MFMA GEMM (z = h @ W1^T bf16, + s,t from f32 acc);
// blocks [G1, G1+G2) = edge partition pass. Disjoint data -> safe overlap.
__global__ __launch_bounds__(256, 4) void k_gp(
    const float* __restrict__ h, const float* __restrict__ W1,
    const float* __restrict__ Wa, unsigned short* __restrict__ zb,
    float* __restrict__ s, float* __restrict__ t, int N, int G1,
    const int* __restrict__ src, const int* __restrict__ dst,
    unsigned* __restrict__ gcur, unsigned* __restrict__ table,
    int E, int NBKT, int BCAP)
{
    __shared__ __align__(16) union SM {
        struct { short wsb[64 * 128]; short tbuf[4][16 * 64]; } g;       // 24 KB
        struct {
            unsigned cnt[256]; unsigned exc[256]; unsigned sbuf[256];
            unsigned gbaseb[256]; unsigned stage[CHUNK];
            unsigned short bkt[CHUNK];
        } p;                                                             // 28 KB
    } sm;
    const int tid = threadIdx.x;

    if (blockIdx.x < (unsigned)G1) {
        // ---------------- GEMM path ----------------
        const int nb = blockIdx.x * 256;
        const int w  = tid >> 6;
        const int l  = tid & 63;
        const int lr = l & 15;
        const int lc = l >> 4;
        const int rowbase = nb + w * 64;
        const float4* __restrict__ h4 = (const float4*)h;
        const float4* __restrict__ W14 = (const float4*)W1;

        float asrc[4], adst[4];
#pragma unroll
        for (int ni = 0; ni < 4; ++ni) {
            asrc[ni] = Wa[ni * 16 + lr];
            adst[ni] = Wa[64 + ni * 16 + lr];
        }

        float4 av[8];
        {
            const int myn = rowbase + lr;
#pragma unroll
            for (int ks = 0; ks < 4; ++ks) {
                const int kcb = ks * 4 + lc;
                if (myn < N) {
                    av[2 * ks]     = h4[(size_t)myn * 32 + kcb * 2];
                    av[2 * ks + 1] = h4[(size_t)myn * 32 + kcb * 2 + 1];
                } else {
                    av[2 * ks]     = make_float4(0.f, 0.f, 0.f, 0.f);
                    av[2 * ks + 1] = make_float4(0.f, 0.f, 0.f, 0.f);
                }
            }
        }

#pragma unroll
        for (int it = 0; it < 4; ++it) {
            const int q = tid + it * 256;
            const int r = q >> 4, cb = q & 15;
            float4 v0 = W14[(size_t)r * 32 + cb * 2];
            float4 v1 = W14[(size_t)r * 32 + cb * 2 + 1];
            short8 o;
            o[0]=f2bf_rne(v0.x); o[1]=f2bf_rne(v0.y); o[2]=f2bf_rne(v0.z); o[3]=f2bf_rne(v0.w);
            o[4]=f2bf_rne(v1.x); o[5]=f2bf_rne(v1.y); o[6]=f2bf_rne(v1.z); o[7]=f2bf_rne(v1.w);
            *(short8*)&sm.g.wsb[r * 128 + ((cb * 8) ^ ((r & 7) << 3))] = o;
        }
        __syncthreads();

        short* __restrict__ tb = sm.g.tbuf[w];      // per-wave, no barriers

#pragma unroll
        for (int rg = 0; rg < 4; ++rg) {
            short8 afr[4];
#pragma unroll
            for (int ks = 0; ks < 4; ++ks) {
                const float4 v0 = av[2 * ks], v1 = av[2 * ks + 1];
                short8 o;
                o[0]=f2bf_rne(v0.x); o[1]=f2bf_rne(v0.y); o[2]=f2bf_rne(v0.z); o[3]=f2bf_rne(v0.w);
                o[4]=f2bf_rne(v1.x); o[5]=f2bf_rne(v1.y); o[6]=f2bf_rne(v1.z); o[7]=f2bf_rne(v1.w);
                afr[ks] = o;
            }
            if (rg < 3) {
                const int myn = rowbase + (rg + 1) * 16 + lr;
#pragma unroll
                for (int ks = 0; ks < 4; ++ks) {
                    const int kcb = ks * 4 + lc;
                    if (myn < N) {
                        av[2 * ks]     = h4[(size_t)myn * 32 + kcb * 2];
                        av[2 * ks + 1] = h4[(size_t)myn * 32 + kcb * 2 + 1];
                    } else {
                        av[2 * ks]     = make_float4(0.f, 0.f, 0.f, 0.f);
                        av[2 * ks + 1] = make_float4(0.f, 0.f, 0.f, 0.f);
                    }
                }
            }

            f32x4 acc[4];
#pragma unroll
            for (int ni = 0; ni < 4; ++ni) acc[ni] = (f32x4){0.f, 0.f, 0.f, 0.f};
#pragma unroll
            for (int ks = 0; ks < 4; ++ks) {
                const int kcb = ks * 4 + lc;
#pragma unroll
                for (int ni = 0; ni < 4; ++ni) {
                    const int wr = ni * 16 + lr;
                    const short8 bf = *(const short8*)&sm.g.wsb[wr * 128 + ((kcb * 8) ^ ((wr & 7) << 3))];
                    acc[ni] = __builtin_amdgcn_mfma_f32_16x16x32_bf16(afr[ks], bf, acc[ni], 0, 0, 0);
                }
            }

            // s,t epilogue (f32 acc). C/D: col = lr, row = lc*4 + r.
#pragma unroll
            for (int r = 0; r < 4; ++r) {
                float ps = 0.f, pt = 0.f;
#pragma unroll
                for (int ni = 0; ni < 4; ++ni) {
                    ps = fmaf(acc[ni][r], asrc[ni], ps);
                    pt = fmaf(acc[ni][r], adst[ni], pt);
                }
#pragma unroll
                for (int m = 1; m < 16; m <<= 1) {
                    ps += __shfl_xor(ps, m);
                    pt += __shfl_xor(pt, m);
                }
                const int node = rowbase + rg * 16 + lc * 4 + r;
                if (lr == 0 && node < N) { s[node] = ps; t[node] = pt; }
            }

            // z transpose via per-wave LDS -> coalesced 16B stores.
#pragma unroll
            for (int ni = 0; ni < 4; ++ni) {
                const int col = ni * 16 + lr;
#pragma unroll
                for (int r = 0; r < 4; ++r) {
                    const int ro = lc * 4 + r;
                    tb[ro * 64 + (((col >> 3) ^ (ro & 7)) << 3) + (col & 7)]
                        = (short)f2bf_rne(acc[ni][r]);
                }
            }
            {
                const int ro = l >> 2;
                const int n = rowbase + rg * 16 + ro;
                if (n < N) {
#pragma unroll
                    for (int j = 0; j < 2; ++j) {
                        const int c = (l & 3) * 2 + j;
                        const short8 v = *(const short8*)&tb[ro * 64 + ((c ^ (ro & 7)) << 3)];
                        *(short8*)&zb[(size_t)n * 64 + c * 8] = v;
                    }
                }
            }
        }
    } else {
        // ---------------- Partition path ----------------
        const int e0 = (blockIdx.x - G1) * CHUNK;
        const int nE = min(CHUNK, E - e0);

        sm.p.cnt[tid] = 0u;
        __syncthreads();
        for (int i = tid; i < nE; i += 256)
            atomicAdd(&sm.p.cnt[(unsigned)dst[e0 + i] >> 9], 1u);
        __syncthreads();

        const unsigned myc = sm.p.cnt[tid];
        if (tid < NBKT && myc > 0u) sm.p.gbaseb[tid] = atomicAdd(&gcur[tid], myc);

        sm.p.sbuf[tid] = myc;
        __syncthreads();
        for (int off = 1; off < 256; off <<= 1) {
            unsigned x = (tid >= off) ? sm.p.sbuf[tid - off] : 0u;
            __syncthreads();
            sm.p.sbuf[tid] += x;
            __syncthreads();
        }
        sm.p.exc[tid] = sm.p.sbuf[tid] - myc;
        __syncthreads();
        sm.p.cnt[tid] = 0u;
        __syncthreads();

        for (int i = tid; i < nE; i += 256) {
            const unsigned d = (unsigned)dst[e0 + i];
            const unsigned b = d >> 9;
            const unsigned pos = sm.p.exc[b] + atomicAdd(&sm.p.cnt[b], 1u);
            sm.p.stage[pos] = ((unsigned)src[e0 + i] << 9) | (d & 511u);
            sm.p.bkt[pos] = (unsigned short)b;
        }
        __syncthreads();

        for (int i = tid; i < nE; i += 256) {
            const unsigned b = sm.p.bkt[i];
            const unsigned off = sm.p.gbaseb[b] + ((unsigned)i - sm.p.exc[b]);
            if (off < (unsigned)BCAP)
                table[(size_t)b * BCAP + off] = sm.p.stage[i];
        }
    }
}

// Pass B (one block of 512 per coarse bucket): recompute global prefix,
// LDS histogram+scan over 512 nodes, then scatter WITH per-edge softmax
// numerator p = exp(leaky(s[src]+t[dst])) and LDS-atomic denominator.
__global__ __launch_bounds__(512) void k_sp(
    const unsigned* __restrict__ table, const unsigned* __restrict__ gcur,
    const float* __restrict__ s, const float* __restrict__ t,
    uint2* __restrict__ edge_ps, unsigned* __restrict__ offsets,
    unsigned* __restrict__ counts, float* __restrict__ invden,
    int N, int NBKT, int BCAP)
{
    __shared__ unsigned ncnt[NPB], nexc[NPB], scur[NPB], sbuf[NPB];
    __shared__ float tlds[NPB], den[NPB];
    __shared__ unsigned basesh;
    const int tid = threadIdx.x;
    const int b = blockIdx.x;
    const int bc = min((int)gcur[b], BCAP);
    const size_t tbo = (size_t)b * BCAP;
    const int node = b * NPB + tid;

    {
        unsigned c = (tid < NBKT) ? min(gcur[tid], (unsigned)BCAP) : 0u;
        sbuf[tid] = c;
        __syncthreads();
        for (int off = 1; off < NPB; off <<= 1) {
            unsigned x = (tid >= off) ? sbuf[tid - off] : 0u;
            __syncthreads();
            sbuf[tid] += x;
            __syncthreads();
        }
        if (tid == 0) basesh = (b == 0) ? 0u : sbuf[b - 1];
    }
    tlds[tid] = (node < N) ? t[node] : 0.f;
    den[tid] = 0.f;
    ncnt[tid] = 0u;
    __syncthreads();
    const unsigned base = basesh;

    for (int i = tid; i < bc; i += NPB)
        atomicAdd(&ncnt[table[tbo + i] & 511u], 1u);
    __syncthreads();

    const unsigned c0 = ncnt[tid];
    sbuf[tid] = c0;
    __syncthreads();
    for (int off = 1; off < NPB; off <<= 1) {
        unsigned x = (tid >= off) ? sbuf[tid - off] : 0u;
        __syncthreads();
        sbuf[tid] += x;
        __syncthreads();
    }
    nexc[tid] = sbuf[tid] - c0;
    scur[tid] = 0u;
    __syncthreads();

    if (node < N) { offsets[node] = base + nexc[tid]; counts[node] = c0; }

    for (int i = tid; i < bc; i += NPB) {
        const unsigned v = table[tbo + i];
        const unsigned l = v & 511u;
        const unsigned sj = v >> 9;
        float e = s[sj] + tlds[l];
        e = (e >= 0.f) ? e : NEG_SLOPE * e;
        const float p = __expf(e);
        const unsigned pos = nexc[l] + atomicAdd(&scur[l], 1u);
        edge_ps[base + pos] = make_uint2(__float_as_uint(p), sj);
        atomicAdd(&den[l], p);
    }
    __syncthreads();
    if (node < N) invden[node] = 1.f / fmaxf(den[tid], 1e-16f);
}

// Pure gather-accumulate: out[node] = invden * sum p_j * z[src_j].
__global__ __launch_bounds__(256) void k_node(
    const unsigned* __restrict__ offsets, const unsigned* __restrict__ counts,
    const uint2* __restrict__ edge_ps, const float* __restrict__ invden,
    const unsigned short* __restrict__ zb, float* __restrict__ out, int N)
{
    const int tid = threadIdx.x;
    const int node = blockIdx.x * 16 + (tid >> 4);
    if (node >= N) return;
    const int wl    = tid & 63;
    const int gbase = wl & ~15;
    const int sub   = wl & 15;
    const int g2    = sub >> 3;        // edge half (0/1)
    const int l8    = sub & 7;         // dim slice

    const unsigned beg = offsets[node];
    const int cnt = (int)counts[node];
    if (cnt == 0) {
        if (sub < 8) {
            const float4 zz = make_float4(0.f, 0.f, 0.f, 0.f);
            *(float4*)&out[(size_t)node * 64 + sub * 8]     = zz;
            *(float4*)&out[(size_t)node * 64 + sub * 8 + 4] = zz;
        }
        return;
    }

    const float invd = invden[node];
    const unsigned short* __restrict__ zrow = zb + l8 * 8;
    float acc[8] = {0.f, 0.f, 0.f, 0.f, 0.f, 0.f, 0.f, 0.f};

    for (int base = 0; base < cnt; base += 16) {
        const int rem = cnt - base;
        uint2 ep = make_uint2(0u, 0u);          // p=0, sj=0 for inactive slots
        if (sub < rem) ep = edge_ps[beg + base + sub];
        const float p = __uint_as_float(ep.x);
        const int  sj = (int)ep.y;

        uint4 vv[8];
#pragma unroll
        for (int k = 0; k < 8; ++k) {
            const int sjj = __shfl(sj, gbase + g2 * 8 + k);
            vv[k] = *(const uint4*)&zrow[(size_t)sjj * 64];
        }
#pragma unroll
        for (int k = 0; k < 8; ++k) {
            const float pj = __shfl(p, gbase + g2 * 8 + k);
            const uint4 v = vv[k];
#define UNPK(u, d0) \
            acc[d0]     = fmaf(pj, __uint_as_float((u) << 16),          acc[d0]); \
            acc[d0 + 1] = fmaf(pj, __uint_as_float((u) & 0xFFFF0000u), acc[d0 + 1]);
            UNPK(v.x, 0) UNPK(v.y, 2) UNPK(v.z, 4) UNPK(v.w, 6)
#undef UNPK
        }
    }

#pragma unroll
    for (int c = 0; c < 8; ++c)
        acc[c] += __shfl_xor(acc[c], 8);

    if (sub < 8) {
        float4 o0 = make_float4(acc[0] * invd, acc[1] * invd, acc[2] * invd, acc[3] * invd);
        float4 o1 = make_float4(acc[4] * invd, acc[5] * invd, acc[6] * invd, acc[7] * invd);
        *(float4*)&out[(size_t)node * 64 + sub * 8]     = o0;
        *(float4*)&out[(size_t)node * 64 + sub * 8 + 4] = o1;
    }
}

extern "C" void kernel_launch(void* const* d_in, const int* in_sizes, int n_in,
                              void* d_out, int out_size, void* d_ws, size_t ws_size,
                              hipStream_t stream) {
    const float* h   = (const float*)d_in[0];
    const int*   src = (const int*)d_in[1];
    const int*   dst = (const int*)d_in[2];
    const float* W1  = (const float*)d_in[3];
    const float* Wa  = (const float*)d_in[4];
    float* out = (float*)d_out;

    const int N = in_sizes[0] / 128;
    const int E = in_sizes[1];
    const int NBKT = (N + NPB - 1) / NPB;            // <=256
    const int meanb = (E + NBKT - 1) / NBKT;
    int slack = 24 * (int)sqrtf((float)meanb) + 64;  // mean + 24 sigma
    const int BCAP = meanb + slack;

    const int G1 = (N + 255) / 256;                  // gemm blocks (256 rows each)
    const int G2 = (E + CHUNK - 1) / CHUNK;          // partition blocks

    // ws: zb(N*64 bf16) | s(N) | t(N) | gcur(NBKT) | offsets(N) | counts(N) |
    //     invden(N) | edge_ps(E u64) | table(NBKT*BCAP)
    unsigned short* zb = (unsigned short*)d_ws;
    float*    s        = (float*)(zb + (size_t)N * 64);
    float*    t        = s + N;
    unsigned* gcur     = (unsigned*)(t + N);
    unsigned* offsets  = gcur + NBKT;
    unsigned* counts   = offsets + N;
    float*    invden   = (float*)(counts + N);
    uint2*    edge_ps  = (uint2*)(invden + N);
    unsigned* table    = (unsigned*)(edge_ps + E);

    hipMemsetAsync(gcur, 0, (size_t)NBKT * sizeof(unsigned), stream);

    k_gp<<<G1 + G2, 256, 0, stream>>>(h, W1, Wa, zb, s, t, N, G1,
                                      src, dst, gcur, table, E, NBKT, BCAP);
    k_sp<<<NBKT, 512, 0, stream>>>(table, gcur, s, t, edge_ps, offsets, counts,
                                   invden, N, NBKT, BCAP);
    k_node<<<(N + 15) / 16, 256, 0, stream>>>(offsets, counts, edge_ps, invden, zb, out, N);
}